// Round 5
// baseline (349.950 us; speedup 1.0000x reference)
//
#include <hip/hip_runtime.h>
#include <stdint.h>

#define D 128
#define CE 2048    // edges per k_part block (4096 entries in LDS)
#define CAP 5120   // fixed bucket capacity (mean 4096 + 16 sigma)

typedef __attribute__((ext_vector_type(8))) __bf16 bf16x8;
typedef __attribute__((ext_vector_type(4))) float floatx4;

union FragU { uint4 u; bf16x8 b; };

__device__ __forceinline__ float bf16_lo(uint32_t u) { return __uint_as_float(u << 16); }
__device__ __forceinline__ float bf16_hi(uint32_t u) { return __uint_as_float(u & 0xffff0000u); }
__device__ __forceinline__ uint16_t f32_to_bf16(float f) {
    uint32_t u = __float_as_uint(f);
    uint32_t r = u + 0x7fffu + ((u >> 16) & 1u);  // round-to-nearest-even
    return (uint16_t)(r >> 16);
}
__device__ __forceinline__ uint32_t pack2(float a, float b) {
    return (uint32_t)f32_to_bf16(a) | ((uint32_t)f32_to_bf16(b) << 16);
}

// Init per-bucket cursors to static bases b*CAP (no count pre-pass needed)
__global__ __launch_bounds__(256) void k_init(uint32_t* __restrict__ gcursor, int nb2)
{
    for (int j = threadIdx.x + blockIdx.x * 256; j < nb2; j += gridDim.x * 256)
        gcursor[j] = (uint32_t)j * CAP;
}

// Partition: block counting-sorts its 2048 edges (x2 dirs) by coarse bucket in LDS,
// reserves per-bucket global runs via gcursor (static bases), streams bucket-sorted
// entries out coalesced. Entry pack: (payload << 8) | (key & 255)
__global__ __launch_bounds__(256) void k_part(
    const int* __restrict__ ei, int E, int nbuk,
    uint32_t* __restrict__ gcursor, uint32_t* __restrict__ gpairs)
{
    __shared__ uint32_t cnt[1024];
    __shared__ uint32_t loff[1024];
    __shared__ uint32_t gbase[1024];
    __shared__ uint32_t spair[2 * CE];
    __shared__ uint16_t sbid[2 * CE];
    __shared__ uint32_t ssum[256];
    int nb2 = 2 * nbuk;
    for (int j = threadIdx.x; j < nb2; j += 256) cnt[j] = 0;
    __syncthreads();
    int base = blockIdx.x * CE;
    int lim = min(CE, E - base);
    for (int i = threadIdx.x; i < lim; i += 256) {
        int r = ei[base + i];
        int c = ei[E + base + i];
        atomicAdd(&cnt[r >> 8], 1u);
        atomicAdd(&cnt[nbuk + (c >> 8)], 1u);
    }
    __syncthreads();
    uint32_t v0 = 0, v1 = 0, v2 = 0, v3 = 0;
    int b0 = threadIdx.x * 4;
    if (b0 < nb2)     v0 = cnt[b0];
    if (b0 + 1 < nb2) v1 = cnt[b0 + 1];
    if (b0 + 2 < nb2) v2 = cnt[b0 + 2];
    if (b0 + 3 < nb2) v3 = cnt[b0 + 3];
    uint32_t tsum = v0 + v1 + v2 + v3;
    ssum[threadIdx.x] = tsum;
    __syncthreads();
    for (int off = 1; off < 256; off <<= 1) {
        uint32_t t = (threadIdx.x >= (unsigned)off) ? ssum[threadIdx.x - off] : 0u;
        __syncthreads();
        ssum[threadIdx.x] += t;
        __syncthreads();
    }
    uint32_t run = ssum[threadIdx.x] - tsum;
    if (b0 < nb2)     loff[b0]     = run;
    if (b0 + 1 < nb2) loff[b0 + 1] = run + v0;
    if (b0 + 2 < nb2) loff[b0 + 2] = run + v0 + v1;
    if (b0 + 3 < nb2) loff[b0 + 3] = run + v0 + v1 + v2;
    __syncthreads();
    for (int j = threadIdx.x; j < nb2; j += 256) {
        uint32_t c2 = cnt[j];
        gbase[j] = c2 ? atomicAdd(&gcursor[j], c2) : 0u;
        cnt[j] = loff[j];
    }
    __syncthreads();
    for (int i = threadIdx.x; i < lim; i += 256) {
        int r = ei[base + i];
        int c = ei[E + base + i];
        int bf = r >> 8;
        uint32_t sf = atomicAdd(&cnt[bf], 1u);
        spair[sf] = ((uint32_t)c << 8) | (uint32_t)(r & 255);
        sbid[sf] = (uint16_t)bf;
        int bb = nbuk + (c >> 8);
        uint32_t sb = atomicAdd(&cnt[bb], 1u);
        spair[sb] = ((uint32_t)r << 8) | (uint32_t)(c & 255);
        sbid[sb] = (uint16_t)bb;
    }
    __syncthreads();
    int total = 2 * lim;
    for (int s2 = threadIdx.x; s2 < total; s2 += 256) {
        int b = sbid[s2];
        gpairs[gbase[b] + ((uint32_t)s2 - loff[b])] = spair[s2];
    }
}

// Fine build: one block per (dir,bucket): 256-key histogram, scan, write ptr/deg/inv,
// scatter payloads into the bucket's L2-hot edata region.
__global__ __launch_bounds__(256) void k_build(
    const uint32_t* __restrict__ gpairs, const uint32_t* __restrict__ gcursor,
    int nbuk, int N,
    int* __restrict__ edata, uint32_t* __restrict__ ptrg, uint32_t* __restrict__ degg,
    float* __restrict__ inv_o, float* __restrict__ inv_i)
{
    __shared__ uint32_t hist[256], cur[256], ssum[256];
    int b = blockIdx.x;
    int dir = (b >= nbuk) ? 1 : 0;
    int node0 = (b - dir * nbuk) << 8;
    uint32_t base = (uint32_t)b * CAP;
    uint32_t cnt_b = gcursor[b] - base;
    hist[threadIdx.x] = 0;
    __syncthreads();
    for (uint32_t i = threadIdx.x; i < cnt_b; i += 256)
        atomicAdd(&hist[gpairs[base + i] & 255u], 1u);
    __syncthreads();
    uint32_t h = hist[threadIdx.x];
    ssum[threadIdx.x] = h;
    __syncthreads();
    for (int off = 1; off < 256; off <<= 1) {
        uint32_t t = (threadIdx.x >= (unsigned)off) ? ssum[threadIdx.x - off] : 0u;
        __syncthreads();
        ssum[threadIdx.x] += t;
        __syncthreads();
    }
    uint32_t excl = ssum[threadIdx.x] - h;
    cur[threadIdx.x] = excl;
    int n = node0 + threadIdx.x;
    if (n < N) {
        ptrg[dir * N + n] = base + excl;
        degg[dir * N + n] = h;
        float iv = h ? rsqrtf((float)h) : 0.0f;
        if (dir == 0) inv_o[n] = iv; else inv_i[n] = iv;
    }
    __syncthreads();
    for (uint32_t i = threadIdx.x; i < cnt_b; i += 256) {
        uint32_t e = gpairs[base + i];
        uint32_t pos = atomicAdd(&cur[e & 255u], 1u);
        edata[base + pos] = (int)(e >> 8);
    }
}

// Fused MFMA projection: ONE x-row read produces BOTH u2 (Wsrc, inv_in folded)
// and v2 (Wdst, inv_out folded). W frags for both mats staged in 64 KB LDS.
// Operand-swapped: D col(lane&15) = node, D row(quad*4+reg) = output channel.
__global__ __launch_bounds__(256) void k_mm(
    const float* __restrict__ x,
    const float* __restrict__ Wsrc, const float* __restrict__ Wdst,
    const float* __restrict__ inv_o, const float* __restrict__ inv_i,
    uint32_t* __restrict__ u2, uint32_t* __restrict__ v2, int N)
{
    __shared__ uint4 sWf[4096];   // 64 KB: [mat][ct*256 + ks*64 + lane]
    const int lane = threadIdx.x & 63;
    const int m16 = lane & 15;
    const int quad = lane >> 4;

    // Stage both W matrices into LDS in MFMA fragment layout (bf16, 0.5 folded)
    {
        uint32_t* sW32 = (uint32_t*)sWf;
        for (int idx = threadIdx.x; idx < 16384; idx += 256) {
            int mat = idx >> 13;
            int rid = idx & 8191;
            int slot = rid >> 2, j2 = rid & 3;
            int ct = slot >> 8, ks = (slot >> 6) & 3, qd = (slot >> 4) & 3, mm = slot & 15;
            const float* Wm = mat ? Wdst : Wsrc;
            const float2 w = *(const float2*)(Wm + (ct * 16 + mm) * 128 + ks * 32 + qd * 8 + 2 * j2);
            sW32[idx] = pack2(0.5f * w.x, 0.5f * w.y);
        }
    }
    __syncthreads();

    const int ntiles = (N + 15) >> 4;
    const int wslot = blockIdx.x * 4 + (threadIdx.x >> 6);
    const int nslot = gridDim.x * 4;

    for (int t = wslot; t < ntiles; t += nslot) {
        int node = t * 16 + m16;
        int rowA = node < N ? node : N - 1;
        const float4* xr = (const float4*)(x + (long)rowA * 128);
        bf16x8 Xf[4];   // B-operand: lane holds x[node][k = ks*32 + quad*8 + j]
        #pragma unroll
        for (int ks = 0; ks < 4; ++ks) {
            float4 p0 = xr[ks * 8 + quad * 2];
            float4 p1 = xr[ks * 8 + quad * 2 + 1];
            FragU f;
            f.u.x = pack2(p0.x, p0.y);
            f.u.y = pack2(p0.z, p0.w);
            f.u.z = pack2(p1.x, p1.y);
            f.u.w = pack2(p1.z, p1.w);
            Xf[ks] = f.b;
        }
        float ivu = inv_i[rowA];   // u2 = (x @ Wsrc^T) * inv_in  (per-src factor)
        float ivv = inv_o[rowA];   // v2 = (x @ Wdst^T) * inv_out (per-src factor)
        bool ok = (node < N);
        #pragma unroll
        for (int ct = 0; ct < 8; ++ct) {
            floatx4 a0 = {}, a1 = {};
            #pragma unroll
            for (int ks = 0; ks < 4; ++ks) {
                FragU w0; w0.u = sWf[ct * 256 + ks * 64 + lane];
                a0 = __builtin_amdgcn_mfma_f32_16x16x32_bf16(w0.b, Xf[ks], a0, 0, 0, 0);
                FragU w1; w1.u = sWf[2048 + ct * 256 + ks * 64 + lane];
                a1 = __builtin_amdgcn_mfma_f32_16x16x32_bf16(w1.b, Xf[ks], a1, 0, 0, 0);
            }
            if (ok) {
                uint2 val0, val1;
                val0.x = pack2(a0[0] * ivu, a0[1] * ivu);
                val0.y = pack2(a0[2] * ivu, a0[3] * ivu);
                val1.x = pack2(a1[0] * ivv, a1[1] * ivv);
                val1.y = pack2(a1[2] * ivv, a1[3] * ivv);
                *(uint2*)(u2 + (long)node * 64 + ct * 8 + quad * 2) = val0;
                *(uint2*)(v2 + (long)node * 64 + ct * 8 + quad * 2) = val1;
            }
        }
    }
}

// Grid-stride over nodes: 2048 long-lived blocks (8 blocks/CU x 4 waves = full
// 32 waves/CU) instead of 12.5k short blocks -> sustained occupancy, more loads
// in flight. Per node: half-wave h handles edge parity h; lane j = lane&31 reads
// dwords (2j,2j+1) = channels 4j..4j+3 (8 B/lane, 256 B/row in one instruction).
__global__ __launch_bounds__(256) void k_gather(
    const uint32_t* __restrict__ u2, const uint32_t* __restrict__ v2,
    const int* __restrict__ edata,
    const uint32_t* __restrict__ ptrg, const uint32_t* __restrict__ degg,
    const float* __restrict__ inv_out, const float* __restrict__ inv_in,
    const float* __restrict__ bsrc, const float* __restrict__ bdst,
    float* __restrict__ out, int N, int nStart, int nEnd)
{
    const int lane = threadIdx.x & 63;
    const int h = lane >> 5;   // edge parity handled by this half-wave
    const int j = lane & 31;   // channel group: 4j..4j+3
    const float4 bs = *(const float4*)(bsrc + 4 * j);
    const float4 bd = *(const float4*)(bdst + 4 * j);
    const int wid = blockIdx.x * 4 + (threadIdx.x >> 6);
    const int nw = gridDim.x * 4;

    for (int node = nStart + wid; node < nEnd; node += nw) {
        uint32_t s0 = ptrg[node],     d0 = degg[node];
        uint32_t s1 = ptrg[N + node], d1 = degg[N + node];
        float io = inv_out[node], ii = inv_in[node];

        float f0 = 0, f1 = 0, f2 = 0, f3 = 0;
        {
            uint32_t k = 0;
            for (; k + 8 <= d0; k += 8) {
                int i0 = edata[s0 + k     + h];
                int i1 = edata[s0 + k + 2 + h];
                int i2 = edata[s0 + k + 4 + h];
                int i3 = edata[s0 + k + 6 + h];
                uint2 p0 = *(const uint2*)(u2 + (long)i0 * 64 + 2 * j);
                uint2 p1 = *(const uint2*)(u2 + (long)i1 * 64 + 2 * j);
                uint2 p2 = *(const uint2*)(u2 + (long)i2 * 64 + 2 * j);
                uint2 p3 = *(const uint2*)(u2 + (long)i3 * 64 + 2 * j);
                f0 += bf16_lo(p0.x) + bf16_lo(p1.x) + bf16_lo(p2.x) + bf16_lo(p3.x);
                f1 += bf16_hi(p0.x) + bf16_hi(p1.x) + bf16_hi(p2.x) + bf16_hi(p3.x);
                f2 += bf16_lo(p0.y) + bf16_lo(p1.y) + bf16_lo(p2.y) + bf16_lo(p3.y);
                f3 += bf16_hi(p0.y) + bf16_hi(p1.y) + bf16_hi(p2.y) + bf16_hi(p3.y);
            }
            for (; k + 2 <= d0; k += 2) {
                int i0 = edata[s0 + k + h];
                uint2 p = *(const uint2*)(u2 + (long)i0 * 64 + 2 * j);
                f0 += bf16_lo(p.x); f1 += bf16_hi(p.x);
                f2 += bf16_lo(p.y); f3 += bf16_hi(p.y);
            }
            if (k < d0 && h == 0) {   // odd leftover edge: parity-0 half only
                int i0 = edata[s0 + k];
                uint2 p = *(const uint2*)(u2 + (long)i0 * 64 + 2 * j);
                f0 += bf16_lo(p.x); f1 += bf16_hi(p.x);
                f2 += bf16_lo(p.y); f3 += bf16_hi(p.y);
            }
        }

        float g0 = 0, g1 = 0, g2 = 0, g3 = 0;
        {
            uint32_t k = 0;
            for (; k + 8 <= d1; k += 8) {
                int i0 = edata[s1 + k     + h];
                int i1 = edata[s1 + k + 2 + h];
                int i2 = edata[s1 + k + 4 + h];
                int i3 = edata[s1 + k + 6 + h];
                uint2 p0 = *(const uint2*)(v2 + (long)i0 * 64 + 2 * j);
                uint2 p1 = *(const uint2*)(v2 + (long)i1 * 64 + 2 * j);
                uint2 p2 = *(const uint2*)(v2 + (long)i2 * 64 + 2 * j);
                uint2 p3 = *(const uint2*)(v2 + (long)i3 * 64 + 2 * j);
                g0 += bf16_lo(p0.x) + bf16_lo(p1.x) + bf16_lo(p2.x) + bf16_lo(p3.x);
                g1 += bf16_hi(p0.x) + bf16_hi(p1.x) + bf16_hi(p2.x) + bf16_hi(p3.x);
                g2 += bf16_lo(p0.y) + bf16_lo(p1.y) + bf16_lo(p2.y) + bf16_lo(p3.y);
                g3 += bf16_hi(p0.y) + bf16_hi(p1.y) + bf16_hi(p2.y) + bf16_hi(p3.y);
            }
            for (; k + 2 <= d1; k += 2) {
                int i0 = edata[s1 + k + h];
                uint2 p = *(const uint2*)(v2 + (long)i0 * 64 + 2 * j);
                g0 += bf16_lo(p.x); g1 += bf16_hi(p.x);
                g2 += bf16_lo(p.y); g3 += bf16_hi(p.y);
            }
            if (k < d1 && h == 0) {
                int i0 = edata[s1 + k];
                uint2 p = *(const uint2*)(v2 + (long)i0 * 64 + 2 * j);
                g0 += bf16_lo(p.x); g1 += bf16_hi(p.x);
                g2 += bf16_lo(p.y); g3 += bf16_hi(p.y);
            }
        }

        // fold the two edge-parities (wave-uniform control flow here)
        f0 += __shfl_xor(f0, 32); f1 += __shfl_xor(f1, 32);
        f2 += __shfl_xor(f2, 32); f3 += __shfl_xor(f3, 32);
        g0 += __shfl_xor(g0, 32); g1 += __shfl_xor(g1, 32);
        g2 += __shfl_xor(g2, 32); g3 += __shfl_xor(g3, 32);

        if (h == 0) {
            float4 o;
            o.x = io * f0 + ii * g0 + 0.5f * (bs.x + bd.x);
            o.y = io * f1 + ii * g1 + 0.5f * (bs.y + bd.y);
            o.z = io * f2 + ii * g2 + 0.5f * (bs.z + bd.z);
            o.w = io * f3 + ii * g3 + 0.5f * (bs.w + bd.w);
            *(float4*)(out + (long)node * 128 + 4 * j) = o;
        }
    }
}

extern "C" void kernel_launch(void* const* d_in, const int* in_sizes, int n_in,
                              void* d_out, int out_size, void* d_ws, size_t ws_size,
                              hipStream_t stream) {
    const int N = in_sizes[0] / D;    // 100000
    const int E = in_sizes[1] / 2;    // 1600000
    const int nbuk = (N + 255) >> 8;  // 391 coarse buckets per direction
    const int nb2 = 2 * nbuk;         // 782

    const float* x    = (const float*)d_in[0];
    const int*   ei   = (const int*)d_in[1];
    const float* Wsrc = (const float*)d_in[2];
    const float* bsrc = (const float*)d_in[3];
    const float* Wdst = (const float*)d_in[4];
    const float* bdst = (const float*)d_in[5];

    char* ws = (char*)d_ws;
    size_t off = 0;
    uint32_t* gcur   = (uint32_t*)(ws + off); off += 1024 * 4;
    float*    inv_o  = (float*)(ws + off);    off += (size_t)N * 4;
    float*    inv_i  = (float*)(ws + off);    off += (size_t)N * 4;
    uint32_t* ptrg   = (uint32_t*)(ws + off); off += (size_t)2 * N * 4;
    uint32_t* degg   = (uint32_t*)(ws + off); off += (size_t)2 * N * 4;
    uint32_t* gpairs = (uint32_t*)(ws + off); off += (size_t)nb2 * CAP * 4;
    int*      edata  = (int*)(ws + off);      off += (size_t)nb2 * CAP * 4;
    uint32_t* u2     = (uint32_t*)(ws + off); off += (size_t)N * 64 * 4;
    uint32_t* v2     = (uint32_t*)(ws + off); off += (size_t)N * 64 * 4;

    k_init<<<4, 256, 0, stream>>>(gcur, nb2);

    k_part<<<(E + CE - 1) / CE, 256, 0, stream>>>(ei, E, nbuk, gcur, gpairs);

    k_build<<<nb2, 256, 0, stream>>>(gpairs, gcur, nbuk, N,
                                     edata, ptrg, degg, inv_o, inv_i);

    k_mm<<<1024, 256, 0, stream>>>(x, Wsrc, Wdst, inv_o, inv_i, u2, v2, N);

    int half = (N + 1) / 2;
    k_gather<<<2048, 256, 0, stream>>>(u2, v2, edata, ptrg, degg,
                                       inv_o, inv_i, bsrc, bdst,
                                       (float*)d_out, N, 0, half);
    k_gather<<<2048, 256, 0, stream>>>(u2, v2, edata, ptrg, degg,
                                       inv_o, inv_i, bsrc, bdst,
                                       (float*)d_out, N, half, N);
}

// Round 6
// 318.477 us; speedup vs baseline: 1.0988x; 1.0988x over previous
//
#include <hip/hip_runtime.h>
#include <stdint.h>

#define D 128
#define CE 2048    // edges per k_part block (4096 entries in LDS)
#define CAP 5120   // fixed bucket capacity (mean 4096 + 16 sigma)

typedef __attribute__((ext_vector_type(8))) __bf16 bf16x8;
typedef __attribute__((ext_vector_type(4))) float floatx4;

union FragU { uint4 u; bf16x8 b; };

__device__ __forceinline__ float bf16_lo(uint32_t u) { return __uint_as_float(u << 16); }
__device__ __forceinline__ float bf16_hi(uint32_t u) { return __uint_as_float(u & 0xffff0000u); }
__device__ __forceinline__ uint16_t f32_to_bf16(float f) {
    uint32_t u = __float_as_uint(f);
    uint32_t r = u + 0x7fffu + ((u >> 16) & 1u);  // round-to-nearest-even
    return (uint16_t)(r >> 16);
}
__device__ __forceinline__ uint32_t pack2(float a, float b) {
    return (uint32_t)f32_to_bf16(a) | ((uint32_t)f32_to_bf16(b) << 16);
}

// Init per-bucket cursors to static bases b*CAP (no count pre-pass needed)
__global__ __launch_bounds__(256) void k_init(uint32_t* __restrict__ gcursor, int nb2)
{
    for (int j = threadIdx.x + blockIdx.x * 256; j < nb2; j += gridDim.x * 256)
        gcursor[j] = (uint32_t)j * CAP;
}

// Partition: block counting-sorts its 2048 edges (x2 dirs) by coarse bucket in LDS,
// reserves per-bucket global runs via gcursor (static bases), streams bucket-sorted
// entries out coalesced. Entry pack: (payload << 8) | (key & 255)
__global__ __launch_bounds__(256) void k_part(
    const int* __restrict__ ei, int E, int nbuk,
    uint32_t* __restrict__ gcursor, uint32_t* __restrict__ gpairs)
{
    __shared__ uint32_t cnt[1024];
    __shared__ uint32_t loff[1024];
    __shared__ uint32_t gbase[1024];
    __shared__ uint32_t spair[2 * CE];
    __shared__ uint16_t sbid[2 * CE];
    __shared__ uint32_t ssum[256];
    int nb2 = 2 * nbuk;
    for (int j = threadIdx.x; j < nb2; j += 256) cnt[j] = 0;
    __syncthreads();
    int base = blockIdx.x * CE;
    int lim = min(CE, E - base);
    for (int i = threadIdx.x; i < lim; i += 256) {
        int r = ei[base + i];
        int c = ei[E + base + i];
        atomicAdd(&cnt[r >> 8], 1u);
        atomicAdd(&cnt[nbuk + (c >> 8)], 1u);
    }
    __syncthreads();
    uint32_t v0 = 0, v1 = 0, v2 = 0, v3 = 0;
    int b0 = threadIdx.x * 4;
    if (b0 < nb2)     v0 = cnt[b0];
    if (b0 + 1 < nb2) v1 = cnt[b0 + 1];
    if (b0 + 2 < nb2) v2 = cnt[b0 + 2];
    if (b0 + 3 < nb2) v3 = cnt[b0 + 3];
    uint32_t tsum = v0 + v1 + v2 + v3;
    ssum[threadIdx.x] = tsum;
    __syncthreads();
    for (int off = 1; off < 256; off <<= 1) {
        uint32_t t = (threadIdx.x >= (unsigned)off) ? ssum[threadIdx.x - off] : 0u;
        __syncthreads();
        ssum[threadIdx.x] += t;
        __syncthreads();
    }
    uint32_t run = ssum[threadIdx.x] - tsum;
    if (b0 < nb2)     loff[b0]     = run;
    if (b0 + 1 < nb2) loff[b0 + 1] = run + v0;
    if (b0 + 2 < nb2) loff[b0 + 2] = run + v0 + v1;
    if (b0 + 3 < nb2) loff[b0 + 3] = run + v0 + v1 + v2;
    __syncthreads();
    for (int j = threadIdx.x; j < nb2; j += 256) {
        uint32_t c2 = cnt[j];
        gbase[j] = c2 ? atomicAdd(&gcursor[j], c2) : 0u;
        cnt[j] = loff[j];
    }
    __syncthreads();
    for (int i = threadIdx.x; i < lim; i += 256) {
        int r = ei[base + i];
        int c = ei[E + base + i];
        int bf = r >> 8;
        uint32_t sf = atomicAdd(&cnt[bf], 1u);
        spair[sf] = ((uint32_t)c << 8) | (uint32_t)(r & 255);
        sbid[sf] = (uint16_t)bf;
        int bb = nbuk + (c >> 8);
        uint32_t sb = atomicAdd(&cnt[bb], 1u);
        spair[sb] = ((uint32_t)r << 8) | (uint32_t)(c & 255);
        sbid[sb] = (uint16_t)bb;
    }
    __syncthreads();
    int total = 2 * lim;
    for (int s2 = threadIdx.x; s2 < total; s2 += 256) {
        int b = sbid[s2];
        gpairs[gbase[b] + ((uint32_t)s2 - loff[b])] = spair[s2];
    }
}

// Fine build: one block per (dir,bucket): 256-key histogram, scan, write ptr/deg/inv.
// Payload scatter goes to LDS (random 4-B LDS writes are cheap), then flushes to
// edata with coalesced int4 stores -> kills the 3.2M scattered global writes.
__global__ __launch_bounds__(256) void k_build(
    const uint32_t* __restrict__ gpairs, const uint32_t* __restrict__ gcursor,
    int nbuk, int N,
    int* __restrict__ edata, uint32_t* __restrict__ ptrg, uint32_t* __restrict__ degg,
    float* __restrict__ inv_o, float* __restrict__ inv_i)
{
    __shared__ uint32_t hist[256], cur[256], ssum[256];
    __shared__ int sdata[CAP];   // 20 KB staging for sorted payloads
    int b = blockIdx.x;
    int dir = (b >= nbuk) ? 1 : 0;
    int node0 = (b - dir * nbuk) << 8;
    uint32_t base = (uint32_t)b * CAP;
    uint32_t cnt_b = gcursor[b] - base;
    hist[threadIdx.x] = 0;
    __syncthreads();
    for (uint32_t i = threadIdx.x; i < cnt_b; i += 256)
        atomicAdd(&hist[gpairs[base + i] & 255u], 1u);
    __syncthreads();
    uint32_t h = hist[threadIdx.x];
    ssum[threadIdx.x] = h;
    __syncthreads();
    for (int off = 1; off < 256; off <<= 1) {
        uint32_t t = (threadIdx.x >= (unsigned)off) ? ssum[threadIdx.x - off] : 0u;
        __syncthreads();
        ssum[threadIdx.x] += t;
        __syncthreads();
    }
    uint32_t excl = ssum[threadIdx.x] - h;
    cur[threadIdx.x] = excl;
    int n = node0 + threadIdx.x;
    if (n < N) {
        ptrg[dir * N + n] = base + excl;
        degg[dir * N + n] = h;
        float iv = h ? rsqrtf((float)h) : 0.0f;
        if (dir == 0) inv_o[n] = iv; else inv_i[n] = iv;
    }
    __syncthreads();
    for (uint32_t i = threadIdx.x; i < cnt_b; i += 256) {
        uint32_t e = gpairs[base + i];
        uint32_t pos = atomicAdd(&cur[e & 255u], 1u);
        sdata[pos] = (int)(e >> 8);
    }
    __syncthreads();
    // coalesced flush: int4 main body + scalar tail (base is 16B-aligned: CAP*4 % 16 == 0)
    uint32_t c4 = cnt_b & ~3u;
    for (uint32_t i = 4 * threadIdx.x; i < c4; i += 1024) {
        *(int4*)&edata[base + i] = *(const int4*)&sdata[i];
    }
    for (uint32_t i = c4 + threadIdx.x; i < cnt_b; i += 256)
        edata[base + i] = sdata[i];
}

// MFMA projection (unfused, round-3 form): one matrix per block (blockIdx&1),
// 32 KB LDS for W frags -> ~5 blocks/CU LDS-wise, decent occupancy.
// Operand-swapped: D col(lane&15) = node, D row(quad*4+reg) = output channel.
__global__ __launch_bounds__(256) void k_mm(
    const float* __restrict__ x,
    const float* __restrict__ Wsrc, const float* __restrict__ Wdst,
    const float* __restrict__ inv_o, const float* __restrict__ inv_i,
    uint32_t* __restrict__ u2, uint32_t* __restrict__ v2, int N)
{
    __shared__ uint4 sWf[2048];   // 32 KB: frag slot = ct*256 + ks*64 + lane
    const int lane = threadIdx.x & 63;
    const int m16 = lane & 15;
    const int quad = lane >> 4;
    const int mat = blockIdx.x & 1;
    uint32_t* outb = mat ? v2 : u2;
    const float* inv = mat ? inv_o : inv_i;
    const float* Wm = mat ? Wdst : Wsrc;   // [128][128] row-major fp32

    // Stage W into LDS in MFMA fragment layout (bf16 pairs, 0.5 folded)
    {
        uint32_t* sW32 = (uint32_t*)sWf;
        for (int idx = threadIdx.x; idx < 8192; idx += 256) {
            int slot = idx >> 2, j2 = idx & 3;
            int ct = slot >> 8, ks = (slot >> 6) & 3, qd = (slot >> 4) & 3, mm = slot & 15;
            const float2 w = *(const float2*)(Wm + (ct * 16 + mm) * 128 + ks * 32 + qd * 8 + 2 * j2);
            sW32[idx] = pack2(0.5f * w.x, 0.5f * w.y);
        }
    }
    __syncthreads();

    const int ntiles = (N + 15) >> 4;
    const int wslot = (blockIdx.x >> 1) * 4 + (threadIdx.x >> 6);
    const int nslot = (gridDim.x >> 1) * 4;

    for (int t = wslot; t < ntiles; t += nslot) {
        int node = t * 16 + m16;
        int rowA = node < N ? node : N - 1;
        const float4* xr = (const float4*)(x + (long)rowA * 128);
        bf16x8 Xf[4];   // B-operand: lane holds x[node][k = ks*32 + quad*8 + j]
        #pragma unroll
        for (int ks = 0; ks < 4; ++ks) {
            float4 p0 = xr[ks * 8 + quad * 2];
            float4 p1 = xr[ks * 8 + quad * 2 + 1];
            FragU f;
            f.u.x = pack2(p0.x, p0.y);
            f.u.y = pack2(p0.z, p0.w);
            f.u.z = pack2(p1.x, p1.y);
            f.u.w = pack2(p1.z, p1.w);
            Xf[ks] = f.b;
        }
        float iv = mat ? inv_o[rowA] : inv_i[rowA];  // per-src factor folded into rows
        bool ok = (node < N);
        #pragma unroll
        for (int ct = 0; ct < 8; ++ct) {
            floatx4 acc = {};
            #pragma unroll
            for (int ks = 0; ks < 4; ++ks) {
                FragU wf; wf.u = sWf[ct * 256 + ks * 64 + lane];
                acc = __builtin_amdgcn_mfma_f32_16x16x32_bf16(wf.b, Xf[ks], acc, 0, 0, 0);
            }
            // lane owns node=node, channels o = ct*16 + quad*4 + {0,1,2,3}
            if (ok) {
                uint2 val;
                val.x = pack2(acc[0] * iv, acc[1] * iv);
                val.y = pack2(acc[2] * iv, acc[3] * iv);
                *(uint2*)(outb + (long)node * 64 + ct * 8 + quad * 2) = val;
            }
        }
    }
}

// Grid-stride over nodes, single launch over [0,N): 2048 long-lived blocks
// (8 blocks/CU x 4 waves = full 32 waves/CU). Per node: half-wave h handles edge
// parity h; lane j = lane&31 reads dwords (2j,2j+1) = channels 4j..4j+3.
__global__ __launch_bounds__(256) void k_gather(
    const uint32_t* __restrict__ u2, const uint32_t* __restrict__ v2,
    const int* __restrict__ edata,
    const uint32_t* __restrict__ ptrg, const uint32_t* __restrict__ degg,
    const float* __restrict__ inv_out, const float* __restrict__ inv_in,
    const float* __restrict__ bsrc, const float* __restrict__ bdst,
    float* __restrict__ out, int N, int nStart, int nEnd)
{
    const int lane = threadIdx.x & 63;
    const int h = lane >> 5;   // edge parity handled by this half-wave
    const int j = lane & 31;   // channel group: 4j..4j+3
    const float4 bs = *(const float4*)(bsrc + 4 * j);
    const float4 bd = *(const float4*)(bdst + 4 * j);
    const int wid = blockIdx.x * 4 + (threadIdx.x >> 6);
    const int nw = gridDim.x * 4;

    for (int node = nStart + wid; node < nEnd; node += nw) {
        uint32_t s0 = ptrg[node],     d0 = degg[node];
        uint32_t s1 = ptrg[N + node], d1 = degg[N + node];
        float io = inv_out[node], ii = inv_in[node];

        float f0 = 0, f1 = 0, f2 = 0, f3 = 0;
        {
            uint32_t k = 0;
            for (; k + 8 <= d0; k += 8) {
                int i0 = edata[s0 + k     + h];
                int i1 = edata[s0 + k + 2 + h];
                int i2 = edata[s0 + k + 4 + h];
                int i3 = edata[s0 + k + 6 + h];
                uint2 p0 = *(const uint2*)(u2 + (long)i0 * 64 + 2 * j);
                uint2 p1 = *(const uint2*)(u2 + (long)i1 * 64 + 2 * j);
                uint2 p2 = *(const uint2*)(u2 + (long)i2 * 64 + 2 * j);
                uint2 p3 = *(const uint2*)(u2 + (long)i3 * 64 + 2 * j);
                f0 += bf16_lo(p0.x) + bf16_lo(p1.x) + bf16_lo(p2.x) + bf16_lo(p3.x);
                f1 += bf16_hi(p0.x) + bf16_hi(p1.x) + bf16_hi(p2.x) + bf16_hi(p3.x);
                f2 += bf16_lo(p0.y) + bf16_lo(p1.y) + bf16_lo(p2.y) + bf16_lo(p3.y);
                f3 += bf16_hi(p0.y) + bf16_hi(p1.y) + bf16_hi(p2.y) + bf16_hi(p3.y);
            }
            for (; k + 2 <= d0; k += 2) {
                int i0 = edata[s0 + k + h];
                uint2 p = *(const uint2*)(u2 + (long)i0 * 64 + 2 * j);
                f0 += bf16_lo(p.x); f1 += bf16_hi(p.x);
                f2 += bf16_lo(p.y); f3 += bf16_hi(p.y);
            }
            if (k < d0 && h == 0) {   // odd leftover edge: parity-0 half only
                int i0 = edata[s0 + k];
                uint2 p = *(const uint2*)(u2 + (long)i0 * 64 + 2 * j);
                f0 += bf16_lo(p.x); f1 += bf16_hi(p.x);
                f2 += bf16_lo(p.y); f3 += bf16_hi(p.y);
            }
        }

        float g0 = 0, g1 = 0, g2 = 0, g3 = 0;
        {
            uint32_t k = 0;
            for (; k + 8 <= d1; k += 8) {
                int i0 = edata[s1 + k     + h];
                int i1 = edata[s1 + k + 2 + h];
                int i2 = edata[s1 + k + 4 + h];
                int i3 = edata[s1 + k + 6 + h];
                uint2 p0 = *(const uint2*)(v2 + (long)i0 * 64 + 2 * j);
                uint2 p1 = *(const uint2*)(v2 + (long)i1 * 64 + 2 * j);
                uint2 p2 = *(const uint2*)(v2 + (long)i2 * 64 + 2 * j);
                uint2 p3 = *(const uint2*)(v2 + (long)i3 * 64 + 2 * j);
                g0 += bf16_lo(p0.x) + bf16_lo(p1.x) + bf16_lo(p2.x) + bf16_lo(p3.x);
                g1 += bf16_hi(p0.x) + bf16_hi(p1.x) + bf16_hi(p2.x) + bf16_hi(p3.x);
                g2 += bf16_lo(p0.y) + bf16_lo(p1.y) + bf16_lo(p2.y) + bf16_lo(p3.y);
                g3 += bf16_hi(p0.y) + bf16_hi(p1.y) + bf16_hi(p2.y) + bf16_hi(p3.y);
            }
            for (; k + 2 <= d1; k += 2) {
                int i0 = edata[s1 + k + h];
                uint2 p = *(const uint2*)(v2 + (long)i0 * 64 + 2 * j);
                g0 += bf16_lo(p.x); g1 += bf16_hi(p.x);
                g2 += bf16_lo(p.y); g3 += bf16_hi(p.y);
            }
            if (k < d1 && h == 0) {
                int i0 = edata[s1 + k];
                uint2 p = *(const uint2*)(v2 + (long)i0 * 64 + 2 * j);
                g0 += bf16_lo(p.x); g1 += bf16_hi(p.x);
                g2 += bf16_lo(p.y); g3 += bf16_hi(p.y);
            }
        }

        // fold the two edge-parities (wave-uniform control flow here)
        f0 += __shfl_xor(f0, 32); f1 += __shfl_xor(f1, 32);
        f2 += __shfl_xor(f2, 32); f3 += __shfl_xor(f3, 32);
        g0 += __shfl_xor(g0, 32); g1 += __shfl_xor(g1, 32);
        g2 += __shfl_xor(g2, 32); g3 += __shfl_xor(g3, 32);

        if (h == 0) {
            float4 o;
            o.x = io * f0 + ii * g0 + 0.5f * (bs.x + bd.x);
            o.y = io * f1 + ii * g1 + 0.5f * (bs.y + bd.y);
            o.z = io * f2 + ii * g2 + 0.5f * (bs.z + bd.z);
            o.w = io * f3 + ii * g3 + 0.5f * (bs.w + bd.w);
            *(float4*)(out + (long)node * 128 + 4 * j) = o;
        }
    }
}

extern "C" void kernel_launch(void* const* d_in, const int* in_sizes, int n_in,
                              void* d_out, int out_size, void* d_ws, size_t ws_size,
                              hipStream_t stream) {
    const int N = in_sizes[0] / D;    // 100000
    const int E = in_sizes[1] / 2;    // 1600000
    const int nbuk = (N + 255) >> 8;  // 391 coarse buckets per direction
    const int nb2 = 2 * nbuk;         // 782

    const float* x    = (const float*)d_in[0];
    const int*   ei   = (const int*)d_in[1];
    const float* Wsrc = (const float*)d_in[2];
    const float* bsrc = (const float*)d_in[3];
    const float* Wdst = (const float*)d_in[4];
    const float* bdst = (const float*)d_in[5];

    char* ws = (char*)d_ws;
    size_t off = 0;
    uint32_t* gcur   = (uint32_t*)(ws + off); off += 1024 * 4;
    float*    inv_o  = (float*)(ws + off);    off += (size_t)N * 4;
    float*    inv_i  = (float*)(ws + off);    off += (size_t)N * 4;
    uint32_t* ptrg   = (uint32_t*)(ws + off); off += (size_t)2 * N * 4;
    uint32_t* degg   = (uint32_t*)(ws + off); off += (size_t)2 * N * 4;
    uint32_t* gpairs = (uint32_t*)(ws + off); off += (size_t)nb2 * CAP * 4;
    int*      edata  = (int*)(ws + off);      off += (size_t)nb2 * CAP * 4;
    uint32_t* u2     = (uint32_t*)(ws + off); off += (size_t)N * 64 * 4;
    uint32_t* v2     = (uint32_t*)(ws + off); off += (size_t)N * 64 * 4;

    k_init<<<4, 256, 0, stream>>>(gcur, nb2);

    k_part<<<(E + CE - 1) / CE, 256, 0, stream>>>(ei, E, nbuk, gcur, gpairs);

    k_build<<<nb2, 256, 0, stream>>>(gpairs, gcur, nbuk, N,
                                     edata, ptrg, degg, inv_o, inv_i);

    k_mm<<<2048, 256, 0, stream>>>(x, Wsrc, Wdst, inv_o, inv_i, u2, v2, N);

    k_gather<<<2048, 256, 0, stream>>>(u2, v2, edata, ptrg, degg,
                                       inv_o, inv_i, bsrc, bdst,
                                       (float*)d_out, N, 0, N);
}

// Round 7
// 297.329 us; speedup vs baseline: 1.1770x; 1.0711x over previous
//
#include <hip/hip_runtime.h>
#include <stdint.h>

#define D 128
#define CE 4096    // edges per k_part block (8192 entries in LDS)
#define CAP 5120   // fixed bucket capacity (mean 4096 + 16 sigma)

typedef __attribute__((ext_vector_type(8))) __bf16 bf16x8;
typedef __attribute__((ext_vector_type(4))) float floatx4;

union FragU { uint4 u; bf16x8 b; };

__device__ __forceinline__ float bf16_lo(uint32_t u) { return __uint_as_float(u << 16); }
__device__ __forceinline__ float bf16_hi(uint32_t u) { return __uint_as_float(u & 0xffff0000u); }
__device__ __forceinline__ uint16_t f32_to_bf16(float f) {
    uint32_t u = __float_as_uint(f);
    uint32_t r = u + 0x7fffu + ((u >> 16) & 1u);  // round-to-nearest-even
    return (uint16_t)(r >> 16);
}
__device__ __forceinline__ uint32_t pack2(float a, float b) {
    return (uint32_t)f32_to_bf16(a) | ((uint32_t)f32_to_bf16(b) << 16);
}

// 256-thread exclusive scan: per-wave shfl_up scan (register-only) + 4-entry
// cross-wave combine. 2 barriers total vs 16 in Hillis-Steele.
__device__ __forceinline__ uint32_t block_excl_scan_256(
    uint32_t val, uint32_t* tmp4, int tid)
{
    int lane = tid & 63, wid = tid >> 6;
    uint32_t inc = val;
    #pragma unroll
    for (int off = 1; off < 64; off <<= 1) {
        uint32_t t = __shfl_up(inc, off, 64);
        if (lane >= off) inc += t;
    }
    if (lane == 63) tmp4[wid] = inc;
    __syncthreads();
    uint32_t wofs = 0;
    #pragma unroll
    for (int w = 0; w < 4; ++w) wofs += (w < wid) ? tmp4[w] : 0u;
    __syncthreads();
    return wofs + inc - val;
}

// Init per-bucket cursors to static bases b*CAP (no count pre-pass needed)
__global__ __launch_bounds__(256) void k_init(uint32_t* __restrict__ gcursor, int nb2)
{
    for (int j = threadIdx.x + blockIdx.x * 256; j < nb2; j += gridDim.x * 256)
        gcursor[j] = (uint32_t)j * CAP;
}

// Partition: block counting-sorts its 4096 edges (x2 dirs) by coarse bucket in LDS,
// reserves per-bucket global runs via gcursor (static bases), streams bucket-sorted
// entries out coalesced. Entry pack: (payload << 8) | (key & 255)
__global__ __launch_bounds__(256) void k_part(
    const int* __restrict__ ei, int E, int nbuk,
    uint32_t* __restrict__ gcursor, uint32_t* __restrict__ gpairs)
{
    __shared__ uint32_t cnt[1024];
    __shared__ uint32_t loff[1024];
    __shared__ uint32_t gbase[1024];
    __shared__ uint32_t spair[2 * CE];
    __shared__ uint16_t sbid[2 * CE];
    __shared__ uint32_t stmp[4];
    int nb2 = 2 * nbuk;
    for (int j = threadIdx.x; j < nb2; j += 256) cnt[j] = 0;
    __syncthreads();
    int base = blockIdx.x * CE;
    int lim = min(CE, E - base);
    for (int i = threadIdx.x; i < lim; i += 256) {
        int r = ei[base + i];
        int c = ei[E + base + i];
        atomicAdd(&cnt[r >> 8], 1u);
        atomicAdd(&cnt[nbuk + (c >> 8)], 1u);
    }
    __syncthreads();
    uint32_t v0 = 0, v1 = 0, v2 = 0, v3 = 0;
    int b0 = threadIdx.x * 4;
    if (b0 < nb2)     v0 = cnt[b0];
    if (b0 + 1 < nb2) v1 = cnt[b0 + 1];
    if (b0 + 2 < nb2) v2 = cnt[b0 + 2];
    if (b0 + 3 < nb2) v3 = cnt[b0 + 3];
    uint32_t tsum = v0 + v1 + v2 + v3;
    uint32_t run = block_excl_scan_256(tsum, stmp, threadIdx.x);
    if (b0 < nb2)     loff[b0]     = run;
    if (b0 + 1 < nb2) loff[b0 + 1] = run + v0;
    if (b0 + 2 < nb2) loff[b0 + 2] = run + v0 + v1;
    if (b0 + 3 < nb2) loff[b0 + 3] = run + v0 + v1 + v2;
    __syncthreads();
    for (int j = threadIdx.x; j < nb2; j += 256) {
        uint32_t c2 = cnt[j];
        gbase[j] = c2 ? atomicAdd(&gcursor[j], c2) : 0u;
        cnt[j] = loff[j];
    }
    __syncthreads();
    for (int i = threadIdx.x; i < lim; i += 256) {
        int r = ei[base + i];
        int c = ei[E + base + i];
        int bf = r >> 8;
        uint32_t sf = atomicAdd(&cnt[bf], 1u);
        spair[sf] = ((uint32_t)c << 8) | (uint32_t)(r & 255);
        sbid[sf] = (uint16_t)bf;
        int bb = nbuk + (c >> 8);
        uint32_t sb = atomicAdd(&cnt[bb], 1u);
        spair[sb] = ((uint32_t)r << 8) | (uint32_t)(c & 255);
        sbid[sb] = (uint16_t)bb;
    }
    __syncthreads();
    int total = 2 * lim;
    for (int s2 = threadIdx.x; s2 < total; s2 += 256) {
        int b = sbid[s2];
        gpairs[gbase[b] + ((uint32_t)s2 - loff[b])] = spair[s2];
    }
}

// Fine build: one block per (dir,bucket): 256-key histogram, wave-scan, write
// ptr/deg/inv. Payload scatter goes to LDS, then flushes coalesced (int4).
__global__ __launch_bounds__(256) void k_build(
    const uint32_t* __restrict__ gpairs, const uint32_t* __restrict__ gcursor,
    int nbuk, int N,
    int* __restrict__ edata, uint32_t* __restrict__ ptrg, uint32_t* __restrict__ degg,
    float* __restrict__ inv_o, float* __restrict__ inv_i)
{
    __shared__ uint32_t hist[256], cur[256], stmp[4];
    __shared__ int sdata[CAP];   // 20 KB staging for sorted payloads
    int b = blockIdx.x;
    int dir = (b >= nbuk) ? 1 : 0;
    int node0 = (b - dir * nbuk) << 8;
    uint32_t base = (uint32_t)b * CAP;
    uint32_t cnt_b = gcursor[b] - base;
    hist[threadIdx.x] = 0;
    __syncthreads();
    for (uint32_t i = threadIdx.x; i < cnt_b; i += 256)
        atomicAdd(&hist[gpairs[base + i] & 255u], 1u);
    __syncthreads();
    uint32_t h = hist[threadIdx.x];
    uint32_t excl = block_excl_scan_256(h, stmp, threadIdx.x);
    cur[threadIdx.x] = excl;
    int n = node0 + threadIdx.x;
    if (n < N) {
        ptrg[dir * N + n] = base + excl;
        degg[dir * N + n] = h;
        float iv = h ? rsqrtf((float)h) : 0.0f;
        if (dir == 0) inv_o[n] = iv; else inv_i[n] = iv;
    }
    __syncthreads();
    for (uint32_t i = threadIdx.x; i < cnt_b; i += 256) {
        uint32_t e = gpairs[base + i];
        uint32_t pos = atomicAdd(&cur[e & 255u], 1u);
        sdata[pos] = (int)(e >> 8);
    }
    __syncthreads();
    // coalesced flush: int4 main body + scalar tail (base is 16B-aligned)
    uint32_t c4 = cnt_b & ~3u;
    for (uint32_t i = 4 * threadIdx.x; i < c4; i += 1024) {
        *(int4*)&edata[base + i] = *(const int4*)&sdata[i];
    }
    for (uint32_t i = c4 + threadIdx.x; i < cnt_b; i += 256)
        edata[base + i] = sdata[i];
}

// MFMA projection, one matrix per block (blockIdx&1), software-pipelined:
// next tile's 8 float4 x-loads are issued BEFORE the current tile's MFMA
// cluster, hiding the ~900-cyc HBM read-once latency under compute (T14).
__global__ __launch_bounds__(256) void k_mm(
    const float* __restrict__ x,
    const float* __restrict__ Wsrc, const float* __restrict__ Wdst,
    const float* __restrict__ inv_o, const float* __restrict__ inv_i,
    uint32_t* __restrict__ u2, uint32_t* __restrict__ v2, int N)
{
    __shared__ uint4 sWf[2048];   // 32 KB: frag slot = ct*256 + ks*64 + lane
    const int lane = threadIdx.x & 63;
    const int m16 = lane & 15;
    const int quad = lane >> 4;
    const int mat = blockIdx.x & 1;
    uint32_t* outb = mat ? v2 : u2;
    const float* inv = mat ? inv_o : inv_i;
    const float* Wm = mat ? Wdst : Wsrc;   // [128][128] row-major fp32

    // Stage W into LDS in MFMA fragment layout (bf16 pairs, 0.5 folded)
    {
        uint32_t* sW32 = (uint32_t*)sWf;
        for (int idx = threadIdx.x; idx < 8192; idx += 256) {
            int slot = idx >> 2, j2 = idx & 3;
            int ct = slot >> 8, ks = (slot >> 6) & 3, qd = (slot >> 4) & 3, mm = slot & 15;
            const float2 w = *(const float2*)(Wm + (ct * 16 + mm) * 128 + ks * 32 + qd * 8 + 2 * j2);
            sW32[idx] = pack2(0.5f * w.x, 0.5f * w.y);
        }
    }
    __syncthreads();

    const int ntiles = (N + 15) >> 4;
    const int wslot = (blockIdx.x >> 1) * 4 + (threadIdx.x >> 6);
    const int nslot = (gridDim.x >> 1) * 4;

    int t = wslot;
    if (t < ntiles) {
        float4 P[8];
        float ivr;
        {
            int node = t * 16 + m16;
            int rowA = node < N ? node : N - 1;
            const float4* xr = (const float4*)(x + (long)rowA * 128);
            #pragma unroll
            for (int ks = 0; ks < 4; ++ks) {
                P[2 * ks]     = xr[ks * 8 + quad * 2];
                P[2 * ks + 1] = xr[ks * 8 + quad * 2 + 1];
            }
            ivr = inv[rowA];
        }
        while (true) {
            int node = t * 16 + m16;
            bool ok = (node < N);
            float iv = ivr;
            // pack current tile (P dead after this)
            bf16x8 Xf[4];
            #pragma unroll
            for (int ks = 0; ks < 4; ++ks) {
                FragU f;
                f.u.x = pack2(P[2 * ks].x,     P[2 * ks].y);
                f.u.y = pack2(P[2 * ks].z,     P[2 * ks].w);
                f.u.z = pack2(P[2 * ks + 1].x, P[2 * ks + 1].y);
                f.u.w = pack2(P[2 * ks + 1].z, P[2 * ks + 1].w);
                Xf[ks] = f.b;
            }
            // issue next tile's loads before the MFMA cluster
            int tn = t + nslot;
            if (tn < ntiles) {
                int noden = tn * 16 + m16;
                int rowN = noden < N ? noden : N - 1;
                const float4* xrn = (const float4*)(x + (long)rowN * 128);
                #pragma unroll
                for (int ks = 0; ks < 4; ++ks) {
                    P[2 * ks]     = xrn[ks * 8 + quad * 2];
                    P[2 * ks + 1] = xrn[ks * 8 + quad * 2 + 1];
                }
                ivr = inv[rowN];
            }
            #pragma unroll
            for (int ct = 0; ct < 8; ++ct) {
                floatx4 acc = {};
                #pragma unroll
                for (int ks = 0; ks < 4; ++ks) {
                    FragU wf; wf.u = sWf[ct * 256 + ks * 64 + lane];
                    acc = __builtin_amdgcn_mfma_f32_16x16x32_bf16(wf.b, Xf[ks], acc, 0, 0, 0);
                }
                // lane owns node=node, channels o = ct*16 + quad*4 + {0,1,2,3}
                if (ok) {
                    uint2 val;
                    val.x = pack2(acc[0] * iv, acc[1] * iv);
                    val.y = pack2(acc[2] * iv, acc[3] * iv);
                    *(uint2*)(outb + (long)node * 64 + ct * 8 + quad * 2) = val;
                }
            }
            if (tn >= ntiles) break;
            t = tn;
        }
    }
}

// Grid-stride over nodes, single launch over [0,N): 2048 long-lived blocks
// (8 blocks/CU x 4 waves = full 32 waves/CU). Per node: half-wave h handles edge
// parity h; lane j = lane&31 reads dwords (2j,2j+1) = channels 4j..4j+3.
// At ~3.65 TB/s fetch-rate and 399 MB/dispatch this sits at the cross-XCD
// compulsory-traffic floor (~360 MB) for a random graph -- done optimizing.
__global__ __launch_bounds__(256) void k_gather(
    const uint32_t* __restrict__ u2, const uint32_t* __restrict__ v2,
    const int* __restrict__ edata,
    const uint32_t* __restrict__ ptrg, const uint32_t* __restrict__ degg,
    const float* __restrict__ inv_out, const float* __restrict__ inv_in,
    const float* __restrict__ bsrc, const float* __restrict__ bdst,
    float* __restrict__ out, int N, int nStart, int nEnd)
{
    const int lane = threadIdx.x & 63;
    const int h = lane >> 5;   // edge parity handled by this half-wave
    const int j = lane & 31;   // channel group: 4j..4j+3
    const float4 bs = *(const float4*)(bsrc + 4 * j);
    const float4 bd = *(const float4*)(bdst + 4 * j);
    const int wid = blockIdx.x * 4 + (threadIdx.x >> 6);
    const int nw = gridDim.x * 4;

    for (int node = nStart + wid; node < nEnd; node += nw) {
        uint32_t s0 = ptrg[node],     d0 = degg[node];
        uint32_t s1 = ptrg[N + node], d1 = degg[N + node];
        float io = inv_out[node], ii = inv_in[node];

        float f0 = 0, f1 = 0, f2 = 0, f3 = 0;
        {
            uint32_t k = 0;
            for (; k + 8 <= d0; k += 8) {
                int i0 = edata[s0 + k     + h];
                int i1 = edata[s0 + k + 2 + h];
                int i2 = edata[s0 + k + 4 + h];
                int i3 = edata[s0 + k + 6 + h];
                uint2 p0 = *(const uint2*)(u2 + (long)i0 * 64 + 2 * j);
                uint2 p1 = *(const uint2*)(u2 + (long)i1 * 64 + 2 * j);
                uint2 p2 = *(const uint2*)(u2 + (long)i2 * 64 + 2 * j);
                uint2 p3 = *(const uint2*)(u2 + (long)i3 * 64 + 2 * j);
                f0 += bf16_lo(p0.x) + bf16_lo(p1.x) + bf16_lo(p2.x) + bf16_lo(p3.x);
                f1 += bf16_hi(p0.x) + bf16_hi(p1.x) + bf16_hi(p2.x) + bf16_hi(p3.x);
                f2 += bf16_lo(p0.y) + bf16_lo(p1.y) + bf16_lo(p2.y) + bf16_lo(p3.y);
                f3 += bf16_hi(p0.y) + bf16_hi(p1.y) + bf16_hi(p2.y) + bf16_hi(p3.y);
            }
            for (; k + 2 <= d0; k += 2) {
                int i0 = edata[s0 + k + h];
                uint2 p = *(const uint2*)(u2 + (long)i0 * 64 + 2 * j);
                f0 += bf16_lo(p.x); f1 += bf16_hi(p.x);
                f2 += bf16_lo(p.y); f3 += bf16_hi(p.y);
            }
            if (k < d0 && h == 0) {   // odd leftover edge: parity-0 half only
                int i0 = edata[s0 + k];
                uint2 p = *(const uint2*)(u2 + (long)i0 * 64 + 2 * j);
                f0 += bf16_lo(p.x); f1 += bf16_hi(p.x);
                f2 += bf16_lo(p.y); f3 += bf16_hi(p.y);
            }
        }

        float g0 = 0, g1 = 0, g2 = 0, g3 = 0;
        {
            uint32_t k = 0;
            for (; k + 8 <= d1; k += 8) {
                int i0 = edata[s1 + k     + h];
                int i1 = edata[s1 + k + 2 + h];
                int i2 = edata[s1 + k + 4 + h];
                int i3 = edata[s1 + k + 6 + h];
                uint2 p0 = *(const uint2*)(v2 + (long)i0 * 64 + 2 * j);
                uint2 p1 = *(const uint2*)(v2 + (long)i1 * 64 + 2 * j);
                uint2 p2 = *(const uint2*)(v2 + (long)i2 * 64 + 2 * j);
                uint2 p3 = *(const uint2*)(v2 + (long)i3 * 64 + 2 * j);
                g0 += bf16_lo(p0.x) + bf16_lo(p1.x) + bf16_lo(p2.x) + bf16_lo(p3.x);
                g1 += bf16_hi(p0.x) + bf16_hi(p1.x) + bf16_hi(p2.x) + bf16_hi(p3.x);
                g2 += bf16_lo(p0.y) + bf16_lo(p1.y) + bf16_lo(p2.y) + bf16_lo(p3.y);
                g3 += bf16_hi(p0.y) + bf16_hi(p1.y) + bf16_hi(p2.y) + bf16_hi(p3.y);
            }
            for (; k + 2 <= d1; k += 2) {
                int i0 = edata[s1 + k + h];
                uint2 p = *(const uint2*)(v2 + (long)i0 * 64 + 2 * j);
                g0 += bf16_lo(p.x); g1 += bf16_hi(p.x);
                g2 += bf16_lo(p.y); g3 += bf16_hi(p.y);
            }
            if (k < d1 && h == 0) {
                int i0 = edata[s1 + k];
                uint2 p = *(const uint2*)(v2 + (long)i0 * 64 + 2 * j);
                g0 += bf16_lo(p.x); g1 += bf16_hi(p.x);
                g2 += bf16_lo(p.y); g3 += bf16_hi(p.y);
            }
        }

        // fold the two edge-parities (wave-uniform control flow here)
        f0 += __shfl_xor(f0, 32); f1 += __shfl_xor(f1, 32);
        f2 += __shfl_xor(f2, 32); f3 += __shfl_xor(f3, 32);
        g0 += __shfl_xor(g0, 32); g1 += __shfl_xor(g1, 32);
        g2 += __shfl_xor(g2, 32); g3 += __shfl_xor(g3, 32);

        if (h == 0) {
            float4 o;
            o.x = io * f0 + ii * g0 + 0.5f * (bs.x + bd.x);
            o.y = io * f1 + ii * g1 + 0.5f * (bs.y + bd.y);
            o.z = io * f2 + ii * g2 + 0.5f * (bs.z + bd.z);
            o.w = io * f3 + ii * g3 + 0.5f * (bs.w + bd.w);
            *(float4*)(out + (long)node * 128 + 4 * j) = o;
        }
    }
}

extern "C" void kernel_launch(void* const* d_in, const int* in_sizes, int n_in,
                              void* d_out, int out_size, void* d_ws, size_t ws_size,
                              hipStream_t stream) {
    const int N = in_sizes[0] / D;    // 100000
    const int E = in_sizes[1] / 2;    // 1600000
    const int nbuk = (N + 255) >> 8;  // 391 coarse buckets per direction
    const int nb2 = 2 * nbuk;         // 782

    const float* x    = (const float*)d_in[0];
    const int*   ei   = (const int*)d_in[1];
    const float* Wsrc = (const float*)d_in[2];
    const float* bsrc = (const float*)d_in[3];
    const float* Wdst = (const float*)d_in[4];
    const float* bdst = (const float*)d_in[5];

    char* ws = (char*)d_ws;
    size_t off = 0;
    uint32_t* gcur   = (uint32_t*)(ws + off); off += 1024 * 4;
    float*    inv_o  = (float*)(ws + off);    off += (size_t)N * 4;
    float*    inv_i  = (float*)(ws + off);    off += (size_t)N * 4;
    uint32_t* ptrg   = (uint32_t*)(ws + off); off += (size_t)2 * N * 4;
    uint32_t* degg   = (uint32_t*)(ws + off); off += (size_t)2 * N * 4;
    uint32_t* gpairs = (uint32_t*)(ws + off); off += (size_t)nb2 * CAP * 4;
    int*      edata  = (int*)(ws + off);      off += (size_t)nb2 * CAP * 4;
    uint32_t* u2     = (uint32_t*)(ws + off); off += (size_t)N * 64 * 4;
    uint32_t* v2     = (uint32_t*)(ws + off); off += (size_t)N * 64 * 4;

    k_init<<<4, 256, 0, stream>>>(gcur, nb2);

    k_part<<<(E + CE - 1) / CE, 256, 0, stream>>>(ei, E, nbuk, gcur, gpairs);

    k_build<<<nb2, 256, 0, stream>>>(gpairs, gcur, nbuk, N,
                                     edata, ptrg, degg, inv_o, inv_i);

    k_mm<<<1024, 256, 0, stream>>>(x, Wsrc, Wdst, inv_o, inv_i, u2, v2, N);

    k_gather<<<2048, 256, 0, stream>>>(u2, v2, edata, ptrg, degg,
                                       inv_o, inv_i, bsrc, bdst,
                                       (float*)d_out, N, 0, N);
}